// Round 1
// baseline (661.912 us; speedup 1.0000x reference)
//
#include <hip/hip_runtime.h>

typedef unsigned short ushort_t;
typedef short short8 __attribute__((ext_vector_type(8)));
typedef float f32x4 __attribute__((ext_vector_type(4)));

#define J_TOT 43
#define J6 13
#define D_DIM 512
#define BT 3136
#define OUTW 168
#define NWG 1075   // 25 * 43

__device__ __forceinline__ unsigned short bf16rne(float f) {
    unsigned u = __builtin_bit_cast(unsigned, f);
    u += 0x7fffu + ((u >> 16) & 1u);
    return (unsigned short)(u >> 16);
}

__device__ __forceinline__ float gelu_f(float v) {
    // tanh-form GELU: v*sigmoid(2t), t = 0.7978845608*(v + 0.044715 v^3)
    float t = v * __builtin_fmaf(v * v, 0.0356774081f, 0.7978845608f);
    float e = __builtin_amdgcn_exp2f(t * 2.8853900818f);   // e^{2t}
    float s = __builtin_amdgcn_rcpf(1.0f + e);
    return __builtin_fmaf(-v, s, v);                        // v - v/(1+e^{2t})
}

__device__ __forceinline__ void async_ld16(const void* gsrc, void* ldst) {
    __builtin_amdgcn_global_load_lds(
        (const __attribute__((address_space(1))) unsigned int*)(unsigned long long)(const char*)gsrc,
        (__attribute__((address_space(3))) unsigned int*)ldst,
        16, 0, 0);
}

// ---------------- fused pre-pass ------------------------------------------
// blocks [0, xbB):            x fp32 -> xb bf16 (same [m][j][k] layout)
// blocks [xbB, xbB+2752):     W1 [j][d][e] fp32 -> W1t [j][e][d] bf16
// blocks [xbB+2752, +43):     W2a/W2b -> W2t [j][16][512] bf16 (o zero-padded), b2 -> b2p
__global__ void prepass_kernel(const float* __restrict__ x, ushort_t* __restrict__ xb, int xbB,
                               const float* __restrict__ W1, ushort_t* __restrict__ W1t,
                               const float* __restrict__ W2a, const float* __restrict__ b2a,
                               const float* __restrict__ W2b, const float* __restrict__ b2b,
                               ushort_t* __restrict__ W2t, float* __restrict__ b2p) {
    __shared__ __align__(16) ushort_t tile[64][72];   // 144B row stride: 16B-aligned, conflict-free
    const int b = blockIdx.x;
    const int t = threadIdx.x;

    if (b < xbB) {                       // ---- x convert: 2048 elems / block, exact
        size_t i = ((size_t)b * 256 + t) * 8;
        float4 f0 = *(const float4*)(x + i);
        float4 f1 = *(const float4*)(x + i + 4);
        union { unsigned short s[8]; uint4 v; } pk;
        pk.s[0] = bf16rne(f0.x); pk.s[1] = bf16rne(f0.y);
        pk.s[2] = bf16rne(f0.z); pk.s[3] = bf16rne(f0.w);
        pk.s[4] = bf16rne(f1.x); pk.s[5] = bf16rne(f1.y);
        pk.s[6] = bf16rne(f1.z); pk.s[7] = bf16rne(f1.w);
        *(uint4*)(xb + i) = pk.v;
        return;
    }
    const int bb = b - xbB;
    if (bb < 2752) {                     // ---- W1 transpose, 64x64 tile, 16B vector stores
        const int d0 = (bb & 7) * 64, e0 = ((bb >> 3) & 7) * 64, j = bb >> 6;
        const float* src = W1 + (size_t)j * D_DIM * D_DIM;
        const int el = t & 63, dl = t >> 6;
#pragma unroll
        for (int i = 0; i < 16; i++) {
            int d = dl + i * 4;
            tile[el][d] = bf16rne(src[(size_t)(d0 + d) * D_DIM + e0 + el]);
        }
        __syncthreads();
        ushort_t* dst = W1t + (size_t)j * D_DIM * D_DIM;
#pragma unroll
        for (int p = 0; p < 2; p++) {
            int idx = p * 256 + t;
            int e = idx >> 3, c = idx & 7;
            uint4 v = *(const uint4*)(&tile[e][c * 8]);
            *(uint4*)(dst + (size_t)(e0 + e) * D_DIM + d0 + c * 8) = v;
        }
        return;
    }
    const int j = bb - 2752;             // ---- W2 pack
    const int odim = (j < J6) ? 6 : 3;
    const float* w = (j < J6) ? (W2a + (size_t)j * D_DIM * 6) : (W2b + (size_t)(j - J6) * D_DIM * 3);
    for (int idx = t; idx < 16 * D_DIM; idx += 256) {
        int o = idx >> 9, k = idx & 511;
        float v = (o < odim) ? w[(size_t)k * odim + o] : 0.0f;
        W2t[(size_t)j * 16 * D_DIM + idx] = bf16rne(v);
    }
    if (t < 16) {
        const float* bbv = (j < J6) ? (b2a + (size_t)j * 6) : (b2b + (size_t)(j - J6) * 3);
        b2p[j * 16 + t] = (t < odim) ? bbv[t] : 0.0f;
    }
}

// ---------------- fused main kernel ---------------------------------------
// 1-D grid 1075 (XCD-bijective remap -> (mt, j)), block 256 = 4 waves.
// Tile 128(m) x 128(n) per nt (4 slabs), BK=32, double-buffered LDS:
//   buf b: A [128][64B] at b*16384, B [128][64B] at b*16384+8192  (32 KB total)
//   h [128][256B] aliases both buffers after the ks loop.
// 2-phase pipeline: issue stage(ks+1) -> ds_read+MFMA(ks) -> barrier (vmcnt drain).
template<int USE_XB>
__global__ __launch_bounds__(256, 3)
void MotionDecoder_36309653520632_kernel(const float* __restrict__ x,
                                         const ushort_t* __restrict__ xb,
                                         const float* __restrict__ b1,
                                         const ushort_t* __restrict__ W1t,
                                         const ushort_t* __restrict__ W2t,
                                         const float* __restrict__ b2p,
                                         float* __restrict__ out) {
    __shared__ __align__(16) unsigned char smem[32768];
    char* hs_base = (char*)smem;

    // bijective XCD chunking: 1075 = 8*134 + 3
    const int bid = blockIdx.x;
    const int xcd = bid & 7, idx = bid >> 3;
    const int wg = (xcd < 3) ? (xcd * 135 + idx) : (405 + (xcd - 3) * 134 + idx);
    const int j  = wg / 25;
    const int mt = wg - j * 25;
    const int m0 = mt * 128;

    const int tid  = threadIdx.x;
    const int lane = tid & 63;
    const int wid  = tid >> 6;
    const int wrow = (wid >> 1) * 64;
    const int wcol = (wid & 1) * 64;

    const ushort_t* w1j = W1t + (size_t)j * D_DIM * D_DIM;
    const ushort_t* w2j = W2t + (size_t)j * 16 * D_DIM;

    // staging geometry: per wave-pass p, 16 rows; lane -> (sub-row = lane>>2, chunk = lane&3)
    // LDS is linear (HW adds lane*16); swizzle applied on the GLOBAL source chunk:
    //   content at (row, c) = global chunk c ^ ((row>>1)&3); read side XORs the same way.
    const int sg_sub = lane >> 2;
    const int sg_c   = lane & 3;
    const ushort_t* aG[2];
    const float*    aGf[2];
    const ushort_t* bG[2];
    int sLd[2];
#pragma unroll
    for (int p = 0; p < 2; p++) {
        int mrow = wid * 32 + p * 16 + sg_sub;          // 0..127 within tile
        int row = m0 + mrow; if (row > BT - 1) row = BT - 1;
        int g = sg_c ^ ((mrow >> 1) & 3);
        sLd[p] = (wid * 32 + p * 16) * 64;              // wave-uniform LDS byte base
        if (USE_XB) aG[p]  = xb + ((size_t)row * J_TOT + j) * D_DIM + g * 8;
        else        aGf[p] = x  + ((size_t)row * J_TOT + j) * D_DIM + g * 8;
        bG[p] = w1j + (size_t)mrow * D_DIM + g * 8;     // B row n = mrow (within nt slab)
    }

    f32x4 acc2[2];
    acc2[0] = (f32x4){0.f, 0.f, 0.f, 0.f};
    acc2[1] = (f32x4){0.f, 0.f, 0.f, 0.f};

    for (int nt = 0; nt < 4; nt++) {
        const int n0 = nt * 128;

        // preload bias + layer-2 fragments for this slab (overlaps the ks loop)
        float bvv[4];
#pragma unroll
        for (int ct = 0; ct < 4; ct++)
            bvv[ct] = b1[j * D_DIM + n0 + wcol + ct * 16 + (lane & 15)];
        short8 wf[4];
#pragma unroll
        for (int kk2 = 0; kk2 < 4; kk2++)
            wf[kk2] = *(const short8*)(w2j + (size_t)(lane & 15) * D_DIM + n0 + kk2 * 32 + (lane >> 4) * 8);

        f32x4 acc[4][4];
#pragma unroll
        for (int a = 0; a < 4; a++)
#pragma unroll
            for (int c = 0; c < 4; c++) acc[a][c] = (f32x4){0.f, 0.f, 0.f, 0.f};

        // ---- prologue: stage ks=0 into buf 0
        float4 a32[2][2];
        if (USE_XB) {
#pragma unroll
            for (int p = 0; p < 2; p++) async_ld16(aG[p], (char*)smem + sLd[p]);
        } else {
#pragma unroll
            for (int p = 0; p < 2; p++) {
                a32[p][0] = *(const float4*)(aGf[p]);
                a32[p][1] = *(const float4*)(aGf[p] + 4);
            }
        }
#pragma unroll
        for (int p = 0; p < 2; p++)
            async_ld16(bG[p] + (size_t)n0 * D_DIM, (char*)smem + 8192 + sLd[p]);
        if (!USE_XB) {
#pragma unroll
            for (int p = 0; p < 2; p++) {
                union { unsigned short s[8]; uint4 v; } pk;
                pk.s[0] = bf16rne(a32[p][0].x); pk.s[1] = bf16rne(a32[p][0].y);
                pk.s[2] = bf16rne(a32[p][0].z); pk.s[3] = bf16rne(a32[p][0].w);
                pk.s[4] = bf16rne(a32[p][1].x); pk.s[5] = bf16rne(a32[p][1].y);
                pk.s[6] = bf16rne(a32[p][1].z); pk.s[7] = bf16rne(a32[p][1].w);
                *(uint4*)((char*)smem + sLd[p] + lane * 16) = pk.v;
            }
        }
        __syncthreads();

        int cur = 0;
        for (int ks = 0; ks < 16; ks++) {
            // ---- issue next-tile staging BEFORE compute (2-phase overlap)
            if (ks < 15) {
                const int kn = ks + 1;
                char* abN = (char*)smem + (cur ^ 1) * 16384;
                if (USE_XB) {
#pragma unroll
                    for (int p = 0; p < 2; p++) async_ld16(aG[p] + kn * 32, abN + sLd[p]);
                } else {
#pragma unroll
                    for (int p = 0; p < 2; p++) {
                        a32[p][0] = *(const float4*)(aGf[p] + kn * 32);
                        a32[p][1] = *(const float4*)(aGf[p] + kn * 32 + 4);
                    }
                }
#pragma unroll
                for (int p = 0; p < 2; p++)
                    async_ld16(bG[p] + (size_t)n0 * D_DIM + kn * 32, abN + 8192 + sLd[p]);
            }
            // ---- ds-read fragments from current buffer (2-way banked = free)
            char* ab  = (char*)smem + cur * 16384;
            char* bb2 = ab + 8192;
            const int chv = lane >> 4;
            short8 af[4], bfr[4];
#pragma unroll
            for (int rt = 0; rt < 4; rt++) {
                int m = wrow + rt * 16 + (lane & 15);
                af[rt] = *(const short8*)(ab + m * 64 + ((chv ^ ((m >> 1) & 3)) * 16));
            }
#pragma unroll
            for (int ct = 0; ct < 4; ct++) {
                int n = wcol + ct * 16 + (lane & 15);
                bfr[ct] = *(const short8*)(bb2 + n * 64 + ((chv ^ ((n >> 1) & 3)) * 16));
            }
#pragma unroll
            for (int rt = 0; rt < 4; rt++)
#pragma unroll
                for (int ct = 0; ct < 4; ct++)
                    acc[rt][ct] = __builtin_amdgcn_mfma_f32_16x16x32_bf16(
                        af[rt], bfr[ct], acc[rt][ct], 0, 0, 0);
            // ---- fallback path: convert + LDS-write A for next tile after MFMA (T14)
            if (!USE_XB && ks < 15) {
                char* abN = (char*)smem + (cur ^ 1) * 16384;
#pragma unroll
                for (int p = 0; p < 2; p++) {
                    union { unsigned short s[8]; uint4 v; } pk;
                    pk.s[0] = bf16rne(a32[p][0].x); pk.s[1] = bf16rne(a32[p][0].y);
                    pk.s[2] = bf16rne(a32[p][0].z); pk.s[3] = bf16rne(a32[p][0].w);
                    pk.s[4] = bf16rne(a32[p][1].x); pk.s[5] = bf16rne(a32[p][1].y);
                    pk.s[6] = bf16rne(a32[p][1].z); pk.s[7] = bf16rne(a32[p][1].w);
                    *(uint4*)(abN + sLd[p] + lane * 16) = pk.v;
                }
            }
            __syncthreads();
            cur ^= 1;
        }

        // ---- bias + GELU -> h (bf16) in LDS (aliases both staging buffers)
#pragma unroll
        for (int ct = 0; ct < 4; ct++) {
            int ncol = wcol + ct * 16 + (lane & 15);
            int c2 = ncol >> 3;
            int boff = (ncol & 7) * 2;
#pragma unroll
            for (int rt = 0; rt < 4; rt++) {
                int mb = wrow + rt * 16 + ((lane >> 4) << 2);
#pragma unroll
                for (int rr = 0; rr < 4; rr++) {
                    float g = gelu_f(acc[rt][ct][rr] + bvv[ct]);
                    int m = mb + rr;
                    *(unsigned short*)(hs_base + m * 256 + ((c2 ^ (m & 15)) * 16) + boff) = bf16rne(g);
                }
            }
        }
        __syncthreads();

        // ---- layer 2: all 4 waves, 32 rows each, K = this 128-col slab
#pragma unroll
        for (int rt = 0; rt < 2; rt++) {
            int m = wid * 32 + rt * 16 + (lane & 15);
#pragma unroll
            for (int kk2 = 0; kk2 < 4; kk2++) {
                int ch = kk2 * 4 + (lane >> 4);
                short8 a2 = *(const short8*)(hs_base + m * 256 + ((ch ^ (m & 15)) * 16));
                acc2[rt] = __builtin_amdgcn_mfma_f32_16x16x32_bf16(a2, wf[kk2], acc2[rt], 0, 0, 0);
            }
        }
        __syncthreads();
    }

    // ---- epilogue: out[m, cb + o] = acc2 + b2
    const int o = lane & 15;
    const int odim = (j < J6) ? 6 : 3;
    const int cb = (j < J6) ? j * 6 : 78 + (j - J6) * 3;
    if (o < odim) {
        float bo = b2p[j * 16 + o];
#pragma unroll
        for (int rt = 0; rt < 2; rt++)
#pragma unroll
            for (int rr = 0; rr < 4; rr++) {
                int m = m0 + wid * 32 + rt * 16 + ((lane >> 4) << 2) + rr;
                if (m < BT) out[(size_t)m * OUTW + cb + o] = acc2[rt][rr] + bo;
            }
    }
}

extern "C" void kernel_launch(void* const* d_in, const int* in_sizes, int n_in,
                              void* d_out, int out_size, void* d_ws, size_t ws_size,
                              hipStream_t stream) {
    const float* x   = (const float*)d_in[0];
    const float* W1  = (const float*)d_in[1];
    const float* b1  = (const float*)d_in[2];
    const float* W2a = (const float*)d_in[3];
    const float* b2a = (const float*)d_in[4];
    const float* W2b = (const float*)d_in[5];
    const float* b2b = (const float*)d_in[6];
    float* out = (float*)d_out;

    // workspace layout
    ushort_t* W1t = (ushort_t*)d_ws;                            // 43*512*512*2 = 22,544,384 B
    ushort_t* W2t = W1t + (size_t)J_TOT * D_DIM * D_DIM;        // 43*16*512*2  =    704,512 B
    float*    b2p = (float*)(W2t + (size_t)J_TOT * 16 * D_DIM); // 43*16*4      =      2,752 B
    size_t head = (size_t)J_TOT * D_DIM * D_DIM * 2
                + (size_t)J_TOT * 16 * D_DIM * 2
                + (size_t)J_TOT * 16 * 4;
    head = (head + 255) & ~(size_t)255;
    const size_t xb_bytes = (size_t)BT * J_TOT * D_DIM * 2;     // 138,084,352 B
    const bool use_xb = (ws_size >= head + xb_bytes);
    ushort_t* xbp = (ushort_t*)((char*)d_ws + head);

    const int xbB = use_xb ? 33712 : 0;   // 3136*43*512 / (8*256)
    prepass_kernel<<<xbB + 2752 + J_TOT, 256, 0, stream>>>(
        x, xbp, xbB, W1, W1t, W2a, b2a, W2b, b2b, W2t, b2p);
    if (use_xb)
        MotionDecoder_36309653520632_kernel<1><<<NWG, 256, 0, stream>>>(
            x, xbp, b1, W1t, W2t, b2p, out);
    else
        MotionDecoder_36309653520632_kernel<0><<<NWG, 256, 0, stream>>>(
            x, xbp, b1, W1t, W2t, b2p, out);
}

// Round 2
// 561.617 us; speedup vs baseline: 1.1786x; 1.1786x over previous
//
#include <hip/hip_runtime.h>

typedef unsigned short ushort_t;
typedef short short8 __attribute__((ext_vector_type(8)));
typedef float f32x4 __attribute__((ext_vector_type(4)));

#define J_TOT 43
#define J6 13
#define D_DIM 512
#define BT 3136
#define OUTW 168
#define MTILES 49              // 3136 / 64, exact
#define NWG (MTILES * J_TOT)   // 2107

__device__ __forceinline__ unsigned short bf16rne(float f) {
    unsigned u = __builtin_bit_cast(unsigned, f);
    u += 0x7fffu + ((u >> 16) & 1u);
    return (unsigned short)(u >> 16);
}

__device__ __forceinline__ float gelu_f(float v) {
    float t = v * __builtin_fmaf(v * v, 0.0356774081f, 0.7978845608f);
    float e = __builtin_amdgcn_exp2f(t * 2.8853900818f);   // e^{2t}
    float s = __builtin_amdgcn_rcpf(1.0f + e);
    return __builtin_fmaf(-v, s, v);                        // v - v/(1+e^{2t})
}

__device__ __forceinline__ void async_ld16(const void* gsrc, void* ldst) {
    __builtin_amdgcn_global_load_lds(
        (const __attribute__((address_space(1))) unsigned int*)(unsigned long long)(const char*)gsrc,
        (__attribute__((address_space(3))) unsigned int*)ldst,
        16, 0, 0);
}

// ---------------- pre-pass: W1 transpose + W2 pack -------------------------
// blocks [0, 2752):  W1 [j][d][e] fp32 -> W1t [j][e][d] bf16 (64x64 tiles)
// blocks [2752, 2795): W2a/W2b -> W2t [j][16][512] bf16 (o zero-padded), b2 -> b2p
__global__ void prepass_kernel(const float* __restrict__ W1, ushort_t* __restrict__ W1t,
                               const float* __restrict__ W2a, const float* __restrict__ b2a,
                               const float* __restrict__ W2b, const float* __restrict__ b2b,
                               ushort_t* __restrict__ W2t, float* __restrict__ b2p) {
    __shared__ __align__(16) ushort_t tile[64][72];
    const int b = blockIdx.x;
    const int t = threadIdx.x;

    if (b < 2752) {
        const int d0 = (b & 7) * 64, e0 = ((b >> 3) & 7) * 64, j = b >> 6;
        const float* src = W1 + (size_t)j * D_DIM * D_DIM;
        const int el = t & 63, dl = t >> 6;
#pragma unroll
        for (int i = 0; i < 16; i++) {
            int d = dl + i * 4;
            tile[el][d] = bf16rne(src[(size_t)(d0 + d) * D_DIM + e0 + el]);
        }
        __syncthreads();
        ushort_t* dst = W1t + (size_t)j * D_DIM * D_DIM;
#pragma unroll
        for (int p = 0; p < 2; p++) {
            int idx = p * 256 + t;
            int e = idx >> 3, c = idx & 7;
            uint4 v = *(const uint4*)(&tile[e][c * 8]);
            *(uint4*)(dst + (size_t)(e0 + e) * D_DIM + d0 + c * 8) = v;
        }
        return;
    }
    const int j = b - 2752;
    const int odim = (j < J6) ? 6 : 3;
    const float* w = (j < J6) ? (W2a + (size_t)j * D_DIM * 6) : (W2b + (size_t)(j - J6) * D_DIM * 3);
    for (int idx = t; idx < 16 * D_DIM; idx += 256) {
        int o = idx >> 9, k = idx & 511;
        float v = (o < odim) ? w[(size_t)k * odim + o] : 0.0f;
        W2t[(size_t)j * 16 * D_DIM + idx] = bf16rne(v);
    }
    if (t < 16) {
        const float* bbv = (j < J6) ? (b2a + (size_t)j * 6) : (b2b + (size_t)(j - J6) * 3);
        b2p[j * 16 + t] = (t < odim) ? bbv[t] : 0.0f;
    }
}

// ---------------- fused main kernel ---------------------------------------
// Block = 512 thr (8 waves), 64 rows x full 512 N, one j. Grid 2107.
// LDS (dynamic 160 KB):
//   A : [0, 65536)                64 rows x 64 chunks(16B), slot = c ^ (row&7)
//   B0/B1/B2 : 65536 + b*32768    512 rows x 4 chunks(16B), slot = c ^ ((row>>1)&3)
//   h : aliases [65536, 131072)   64 rows x 64 chunks(16B), slot = c ^ (row&7)
// Pipeline: depth-2 counted vmcnt (never 0 in steady loop), 2 raw barriers/step.
__global__ __launch_bounds__(512, 2)
void MotionDecoder_36309653520632_kernel(const float* __restrict__ x,
                                         const float* __restrict__ b1,
                                         const ushort_t* __restrict__ W1t,
                                         const ushort_t* __restrict__ W2t,
                                         const float* __restrict__ b2p,
                                         float* __restrict__ out) {
    extern __shared__ __align__(16) char smem[];
    char* As = smem;
    char* B0 = smem + 65536;
    char* B1 = smem + 98304;
    char* B2 = smem + 131072;
    char* hs = smem + 65536;

    // bijective XCD chunking: 2107 = 8*263 + 3
    const int bid = blockIdx.x;
    const int xcd = bid & 7, bi = bid >> 3;
    const int wg = (xcd < 3) ? (xcd * 264 + bi) : (792 + (xcd - 3) * 263 + bi);
    const int j  = wg / MTILES;
    const int mt = wg - j * MTILES;
    const int m0 = mt * 64;

    const int tid  = threadIdx.x;
    const int lane = tid & 63;
    const int w    = tid >> 6;       // 0..7
    const int l15  = lane & 15;
    const int l4   = lane >> 4;

    const ushort_t* w1j = W1t + (size_t)j * D_DIM * D_DIM;

    // ---- B staging geometry: wave w stages rows [w*64, w*64+64), 4 passes of 16 rows
    const ushort_t* bGp0; const ushort_t* bGp1; const ushort_t* bGp2; const ushort_t* bGp3;
    int sB0, sB1, sB2, sB3;
    {
        int rbase = w * 64;
#pragma unroll
        for (int p = 0; p < 4; p++) {
            int rw  = rbase + p * 16;
            int row = rw + (lane >> 2);
            int g   = (lane & 3) ^ ((row >> 1) & 3);
            const ushort_t* gp = w1j + (size_t)row * D_DIM + g * 8;
            int s = rw * 64;
            if (p == 0) { bGp0 = gp; sB0 = s; }
            else if (p == 1) { bGp1 = gp; sB1 = s; }
            else if (p == 2) { bGp2 = gp; sB2 = s; }
            else { bGp3 = gp; sB3 = s; }
        }
    }

#define STAGE_B(buf, kk) do { \
        async_ld16(bGp0 + (kk) * 32, (buf) + sB0); \
        async_ld16(bGp1 + (kk) * 32, (buf) + sB1); \
        async_ld16(bGp2 + (kk) * 32, (buf) + sB2); \
        async_ld16(bGp3 + (kk) * 32, (buf) + sB3); \
    } while (0)

    // ---- prologue: load x (once, fp32), stage B(0),B(1), pack A -> LDS bf16
    const int xr = tid >> 3;            // 0..63
    const int c8 = tid & 7;
    const float* xrow = x + ((size_t)(m0 + xr) * J_TOT + j) * D_DIM + c8 * 8;

    float4 xv[16];
#pragma unroll
    for (int i = 0; i < 8; i++) {
        xv[2 * i]     = *(const float4*)(xrow + i * 64);
        xv[2 * i + 1] = *(const float4*)(xrow + i * 64 + 4);
    }
    STAGE_B(B0, 0);
    STAGE_B(B1, 1);
    {
        const int swr = xr & 7;
#pragma unroll
        for (int i = 0; i < 8; i++) {
            union { unsigned short s[8]; uint4 v; } pk;
            float4 f0 = xv[2 * i], f1 = xv[2 * i + 1];
            pk.s[0] = bf16rne(f0.x); pk.s[1] = bf16rne(f0.y);
            pk.s[2] = bf16rne(f0.z); pk.s[3] = bf16rne(f0.w);
            pk.s[4] = bf16rne(f1.x); pk.s[5] = bf16rne(f1.y);
            pk.s[6] = bf16rne(f1.z); pk.s[7] = bf16rne(f1.w);
            int c = c8 + i * 8;
            *(uint4*)(As + xr * 1024 + ((c ^ swr) << 4)) = pk.v;
        }
    }
    // preload layer-1 bias for this wave's n-slab (before the loop; L2-hot)
    float bvv[4];
#pragma unroll
    for (int ct = 0; ct < 4; ct++)
        bvv[ct] = b1[j * D_DIM + w * 64 + ct * 16 + l15];

    asm volatile("s_waitcnt lgkmcnt(0)" ::: "memory");
    __builtin_amdgcn_s_barrier();
    __builtin_amdgcn_sched_barrier(0);

    f32x4 acc[4][4];
#pragma unroll
    for (int a = 0; a < 4; a++)
#pragma unroll
        for (int c = 0; c < 4; c++) acc[a][c] = (f32x4){0.f, 0.f, 0.f, 0.f};

    // ---- main loop: 16 K-steps of 32, depth-2 B prefetch, counted vmcnt
    char* bufA = B0; char* bufB = B1; char* bufC = B2;
    for (int ks = 0; ks < 16; ks++) {
        if (ks < 14) {
            STAGE_B(bufC, ks + 2);
            asm volatile("s_waitcnt vmcnt(8)" ::: "memory");   // B(ks) landed (FIFO)
        } else if (ks == 14) {
            asm volatile("s_waitcnt vmcnt(4)" ::: "memory");
        } else {
            asm volatile("s_waitcnt vmcnt(0)" ::: "memory");
        }
        __builtin_amdgcn_s_barrier();           // A: B(ks) visible to all waves
        __builtin_amdgcn_sched_barrier(0);

        short8 af[4], bf[4];
#pragma unroll
        for (int rt = 0; rt < 4; rt++) {
            int m = rt * 16 + l15;
            int q = ks * 4 + l4;
            af[rt] = *(const short8*)(As + m * 1024 + (((q ^ (m & 7))) << 4));
        }
#pragma unroll
        for (int ct = 0; ct < 4; ct++) {
            int n = w * 64 + ct * 16 + l15;
            bf[ct] = *(const short8*)(bufA + n * 64 + ((l4 ^ ((n >> 1) & 3)) << 4));
        }
        asm volatile("s_waitcnt lgkmcnt(0)" ::: "memory");
        __builtin_amdgcn_s_barrier();           // B: all reads done -> buf reusable
        __builtin_amdgcn_sched_barrier(0);

        __builtin_amdgcn_s_setprio(1);
#pragma unroll
        for (int rt = 0; rt < 4; rt++)
#pragma unroll
            for (int ct = 0; ct < 4; ct++)
                acc[rt][ct] = __builtin_amdgcn_mfma_f32_16x16x32_bf16(
                    af[rt], bf[ct], acc[rt][ct], 0, 0, 0);
        __builtin_amdgcn_s_setprio(0);

        char* tmp = bufA; bufA = bufB; bufB = bufC; bufC = tmp;
    }

    // ---- bias + GELU -> h (bf16) in LDS (aliases B0/B1)
#pragma unroll
    for (int ct = 0; ct < 4; ct++) {
        int n = w * 64 + ct * 16 + l15;
        int cc = n >> 3, boff = (n & 7) * 2;
#pragma unroll
        for (int rt = 0; rt < 4; rt++) {
            int mb = rt * 16 + (l4 << 2);
#pragma unroll
            for (int rr = 0; rr < 4; rr++) {
                int m = mb + rr;
                float g = gelu_f(acc[rt][ct][rr] + bvv[ct]);
                *(unsigned short*)(hs + m * 1024 + (((cc ^ (m & 7))) << 4) + boff) = bf16rne(g);
            }
        }
    }
    __syncthreads();

    // ---- layer 2: waves 0-3, 16 rows each, K = 512
    if (w < 4) {
        const ushort_t* w2j = W2t + (size_t)j * 16 * D_DIM + (size_t)l15 * D_DIM + l4 * 8;
        f32x4 a2acc = (f32x4){0.f, 0.f, 0.f, 0.f};
        const int m = w * 16 + l15;
#pragma unroll
        for (int kc = 0; kc < 16; kc++) {
            short8 wf = *(const short8*)(w2j + kc * 32);
            int q = kc * 4 + l4;
            short8 a2 = *(const short8*)(hs + m * 1024 + (((q ^ (m & 7))) << 4));
            a2acc = __builtin_amdgcn_mfma_f32_16x16x32_bf16(a2, wf, a2acc, 0, 0, 0);
        }
        const int o = l15;
        const int odim = (j < J6) ? 6 : 3;
        const int cb = (j < J6) ? j * 6 : 78 + (j - J6) * 3;
        if (o < odim) {
            float bo = b2p[j * 16 + o];
#pragma unroll
            for (int rr = 0; rr < 4; rr++) {
                int mm = m0 + w * 16 + (l4 << 2) + rr;
                out[(size_t)mm * OUTW + cb + o] = a2acc[rr] + bo;
            }
        }
    }
#undef STAGE_B
}

extern "C" void kernel_launch(void* const* d_in, const int* in_sizes, int n_in,
                              void* d_out, int out_size, void* d_ws, size_t ws_size,
                              hipStream_t stream) {
    const float* x   = (const float*)d_in[0];
    const float* W1  = (const float*)d_in[1];
    const float* b1  = (const float*)d_in[2];
    const float* W2a = (const float*)d_in[3];
    const float* b2a = (const float*)d_in[4];
    const float* W2b = (const float*)d_in[5];
    const float* b2b = (const float*)d_in[6];
    float* out = (float*)d_out;

    // workspace layout
    ushort_t* W1t = (ushort_t*)d_ws;                            // 43*512*512*2 = 22,544,384 B
    ushort_t* W2t = W1t + (size_t)J_TOT * D_DIM * D_DIM;        // 43*16*512*2  =    704,512 B
    float*    b2p = (float*)(W2t + (size_t)J_TOT * 16 * D_DIM); // 43*16*4      =      2,752 B

    static bool attr_set = false;
    if (!attr_set) {
        (void)hipFuncSetAttribute(
            reinterpret_cast<const void*>(MotionDecoder_36309653520632_kernel),
            hipFuncAttributeMaxDynamicSharedMemorySize, 163840);
        attr_set = true;
    }

    prepass_kernel<<<2752 + J_TOT, 256, 0, stream>>>(W1, W1t, W2a, b2a, W2b, b2b, W2t, b2p);
    MotionDecoder_36309653520632_kernel<<<NWG, 512, 163840, stream>>>(
        x, b1, W1t, W2t, b2p, out);
}

// Round 3
// 540.458 us; speedup vs baseline: 1.2247x; 1.0391x over previous
//
#include <hip/hip_runtime.h>

typedef unsigned short ushort_t;
typedef short short8 __attribute__((ext_vector_type(8)));
typedef float f32x4 __attribute__((ext_vector_type(4)));

#define J_TOT 43
#define J6 13
#define D_DIM 512
#define BT 3136
#define OUTW 168
#define MTILES 49              // 3136 / 64, exact
#define NWG (MTILES * J_TOT)   // 2107

__device__ __forceinline__ unsigned short bf16rne(float f) {
    unsigned u = __builtin_bit_cast(unsigned, f);
    u += 0x7fffu + ((u >> 16) & 1u);
    return (unsigned short)(u >> 16);
}

__device__ __forceinline__ float gelu_f(float v) {
    float t = v * __builtin_fmaf(v * v, 0.0356774081f, 0.7978845608f);
    float e = __builtin_amdgcn_exp2f(t * 2.8853900818f);   // e^{2t}
    float s = __builtin_amdgcn_rcpf(1.0f + e);
    return __builtin_fmaf(-v, s, v);                        // v - v/(1+e^{2t})
}

// ---------------- pre-pass: W1 + W2 -> MFMA-fragment-major bf16 -------------
// W1f layout: [(j*8+w)*16+ks][nt(4)][lane(64)][8 bf16]   (1 KB per (.,nt))
//   value = W1[j][ ks*32+(l>>4)*8+idx ][ w*64+nt*16+(l&15) ]
// W2f layout: [j][kc(16)][lane(64)][8 bf16]  (o zero-padded to 16)
//   value = W2[j][ kc*32+(l>>4)*8+idx ][ l&15 ]
__global__ void pack_kernel(const float* __restrict__ W1, ushort_t* __restrict__ W1f,
                            const float* __restrict__ W2a, const float* __restrict__ b2a,
                            const float* __restrict__ W2b, const float* __restrict__ b2b,
                            ushort_t* __restrict__ W2f, float* __restrict__ b2p) {
    const int b = blockIdx.x;
    const int t = threadIdx.x;
    if (b < 5504) {                       // 43*8*16 W1 blocks
        const int j = b >> 7, ks = b & 15, w = (b >> 4) & 7;
        const int nt = t >> 6, l = t & 63;
        const float* src = W1 + (size_t)j * D_DIM * D_DIM;
        const int k0 = ks * 32 + (l >> 4) * 8;
        const int n  = w * 64 + nt * 16 + (l & 15);
        union { unsigned short s[8]; uint4 v; } pk;
#pragma unroll
        for (int idx = 0; idx < 8; idx++)
            pk.s[idx] = bf16rne(src[(size_t)(k0 + idx) * D_DIM + n]);
        *(uint4*)(W1f + ((size_t)b * 4 + nt) * 512 + (size_t)l * 8) = pk.v;
        return;
    }
    const int j = b - 5504;
    const int odim = (j < J6) ? 6 : 3;
    const float* wsrc = (j < J6) ? (W2a + (size_t)j * D_DIM * 6)
                                 : (W2b + (size_t)(j - J6) * D_DIM * 3);
#pragma unroll
    for (int p = 0; p < 4; p++) {
        int ch = p * 256 + t;             // 0..1023 = kc*64 + l
        int l = ch & 63;
        int n0 = (ch >> 6) * 32 + (l >> 4) * 8;
        int o  = l & 15;
        union { unsigned short s[8]; uint4 v; } pk;
#pragma unroll
        for (int idx = 0; idx < 8; idx++) {
            float v = (o < odim) ? wsrc[(size_t)(n0 + idx) * odim + o] : 0.0f;
            pk.s[idx] = bf16rne(v);
        }
        *(uint4*)(W2f + (size_t)j * 8192 + (size_t)ch * 8) = pk.v;
    }
    if (t < 16) {
        const float* bbv = (j < J6) ? (b2a + (size_t)j * 6) : (b2b + (size_t)(j - J6) * 3);
        b2p[j * 16 + t] = (t < odim) ? bbv[t] : 0.0f;
    }
}

// ---------------- fused main kernel ---------------------------------------
// Block = 512 thr (8 waves), 64 rows x full 512 N, one j. Grid 2107.
// LDS 64 KB static -> 2 blocks/CU. x [64 rows][64 chunks16B], slot=(c+row)&63.
// K-loop: W1 frags global->reg (coalesced 1KB), x frags LDS->reg, 16 MFMA.
// NO barriers in the K-loop. h (bf16) aliases x after a barrier; layer-2 on
// all 8 waves (4 m-tiles x 2 K-halves) + padded-stride LDS reduction.
__global__ __launch_bounds__(512, 4)
void MotionDecoder_36309653520632_kernel(const float* __restrict__ x,
                                         const float* __restrict__ b1,
                                         const ushort_t* __restrict__ W1f,
                                         const ushort_t* __restrict__ W2f,
                                         const float* __restrict__ b2p,
                                         float* __restrict__ out) {
    __shared__ __align__(16) unsigned char smem[65536];

    // bijective XCD chunking: 2107 = 8*263 + 3
    const int bid = blockIdx.x;
    const int xcd = bid & 7, bi = bid >> 3;
    const int wg = (xcd < 3) ? (xcd * 264 + bi) : (792 + (xcd - 3) * 263 + bi);
    const int j  = wg / MTILES;
    const int mt = wg - j * MTILES;
    const int m0 = mt * 64;

    const int tid  = threadIdx.x;
    const int lane = tid & 63;
    const int w    = tid >> 6;
    const int l15  = lane & 15;
    const int l4   = lane >> 4;

    // ---- prologue: x fp32 -> bf16 -> LDS (once; 2 reg-pressure-limited passes)
    const int xr = tid >> 3, c8 = tid & 7;
    const float* xrow = x + ((size_t)(m0 + xr) * J_TOT + j) * D_DIM;
#pragma unroll
    for (int g = 0; g < 2; g++) {
        float4 f[8];
#pragma unroll
        for (int i = 0; i < 4; i++) {
            int c = c8 + (g * 4 + i) * 8;
            f[2 * i]     = *(const float4*)(xrow + c * 8);
            f[2 * i + 1] = *(const float4*)(xrow + c * 8 + 4);
        }
#pragma unroll
        for (int i = 0; i < 4; i++) {
            int c = c8 + (g * 4 + i) * 8;
            union { unsigned short s[8]; uint4 v; } pk;
            float4 f0 = f[2 * i], f1 = f[2 * i + 1];
            pk.s[0] = bf16rne(f0.x); pk.s[1] = bf16rne(f0.y);
            pk.s[2] = bf16rne(f0.z); pk.s[3] = bf16rne(f0.w);
            pk.s[4] = bf16rne(f1.x); pk.s[5] = bf16rne(f1.y);
            pk.s[6] = bf16rne(f1.z); pk.s[7] = bf16rne(f1.w);
            *(uint4*)(smem + xr * 1024 + (((c + xr) & 63) << 4)) = pk.v;
        }
    }
    __syncthreads();

    // ---- K-loop: no barriers, double-buffered W1 fragments in registers
    const ushort_t* w1f = W1f + ((size_t)j * 8 + w) * 32768 + (size_t)lane * 8;

    f32x4 acc[4][4];
#pragma unroll
    for (int a = 0; a < 4; a++)
#pragma unroll
        for (int c = 0; c < 4; c++) acc[a][c] = (f32x4){0.f, 0.f, 0.f, 0.f};

    short8 awA[4], awB[4];
#pragma unroll
    for (int nt = 0; nt < 4; nt++)
        awA[nt] = *(const short8*)(w1f + nt * 512);

#define K_STEP(CUR, NXT, KS) do {                                              \
        if ((KS) < 15) {                                                       \
            _Pragma("unroll")                                                  \
            for (int nt = 0; nt < 4; nt++)                                     \
                NXT[nt] = *(const short8*)(w1f + (((KS) + 1) * 4 + nt) * 512); \
        }                                                                      \
        short8 bx[4];                                                          \
        _Pragma("unroll")                                                      \
        for (int mm = 0; mm < 4; mm++) {                                       \
            int m = mm * 16 + l15;                                             \
            bx[mm] = *(const short8*)(smem + m * 1024 +                        \
                        ((((KS) * 4 + l4 + m) & 63) << 4));                    \
        }                                                                      \
        __builtin_amdgcn_s_setprio(1);                                         \
        _Pragma("unroll")                                                      \
        for (int nt = 0; nt < 4; nt++)                                         \
            _Pragma("unroll")                                                  \
            for (int mm = 0; mm < 4; mm++)                                     \
                acc[nt][mm] = __builtin_amdgcn_mfma_f32_16x16x32_bf16(         \
                    CUR[nt], bx[mm], acc[nt][mm], 0, 0, 0);                    \
        __builtin_amdgcn_s_setprio(0);                                         \
    } while (0)

#pragma unroll
    for (int ks2 = 0; ks2 < 8; ks2++) {
        K_STEP(awA, awB, 2 * ks2);
        K_STEP(awB, awA, 2 * ks2 + 1);
    }
#undef K_STEP

    __syncthreads();   // all x-LDS reads done; h overwrites x

    // ---- bias + GELU -> h bf16 in LDS, packed b64 along n (conflict-free)
    const float* b1j = b1 + j * D_DIM + w * 64;
#pragma unroll
    for (int nt = 0; nt < 4; nt++) {
        const int nb = nt * 16 + l4 * 4;           // n within wave slab
        const int c    = (w * 64 + nb) >> 3;       // 16B chunk
        const int half = (nb >> 2) & 1;
#pragma unroll
        for (int mm = 0; mm < 4; mm++) {
            int m = mm * 16 + l15;
            union { unsigned short s[4]; uint2 v; } pk;
#pragma unroll
            for (int rr = 0; rr < 4; rr++) {
                float g = gelu_f(acc[nt][mm][rr] + b1j[nb + rr]);
                pk.s[rr] = bf16rne(g);
            }
            *(uint2*)(smem + m * 1024 + (((c + m) & 63) << 4) + half * 8) = pk.v;
        }
    }
    __syncthreads();

    // ---- layer 2: wave w -> m-tile (w&3), K-half (w>>2); 8 MFMA
    const int mt2 = w & 3, kh = w >> 2;
    const ushort_t* w2f = W2f + (size_t)j * 8192 + (size_t)lane * 8;
    const int m2 = mt2 * 16 + l15;
    f32x4 acc2 = (f32x4){0.f, 0.f, 0.f, 0.f};
#pragma unroll
    for (int kc2 = 0; kc2 < 8; kc2++) {
        int kc = kh * 8 + kc2;
        short8 wfr = *(const short8*)(w2f + kc * 512);
        int q = kc * 4 + l4;
        short8 a2 = *(const short8*)(smem + m2 * 1024 + (((q + m2) & 63) << 4));
        acc2 = __builtin_amdgcn_mfma_f32_16x16x32_bf16(a2, wfr, acc2, 0, 0, 0);
    }
    __syncthreads();   // h reads done -> reduction buffer may alias

    // ---- cross-half reduction (stride-17 pad) + epilogue
    float* red = (float*)smem;             // [64 mrow][17] f32 = 4352 B
    if (w >= 4) {
#pragma unroll
        for (int rr = 0; rr < 4; rr++) {
            int mrow = mt2 * 16 + l4 * 4 + rr;
            red[mrow * 17 + l15] = acc2[rr];
        }
    }
    __syncthreads();
    if (w < 4) {
        const int o = l15;
        const int odim = (j < J6) ? 6 : 3;
        const int cb = (j < J6) ? j * 6 : 78 + (j - J6) * 3;
        if (o < odim) {
            float bo = b2p[j * 16 + o];
#pragma unroll
            for (int rr = 0; rr < 4; rr++) {
                int mrow = mt2 * 16 + l4 * 4 + rr;
                float v = acc2[rr] + red[mrow * 17 + l15] + bo;
                out[(size_t)(m0 + mrow) * OUTW + cb + o] = v;
            }
        }
    }
}

extern "C" void kernel_launch(void* const* d_in, const int* in_sizes, int n_in,
                              void* d_out, int out_size, void* d_ws, size_t ws_size,
                              hipStream_t stream) {
    const float* x   = (const float*)d_in[0];
    const float* W1  = (const float*)d_in[1];
    const float* b1  = (const float*)d_in[2];
    const float* W2a = (const float*)d_in[3];
    const float* b2a = (const float*)d_in[4];
    const float* W2b = (const float*)d_in[5];
    const float* b2b = (const float*)d_in[6];
    float* out = (float*)d_out;

    // workspace layout (same footprint as before)
    ushort_t* W1f = (ushort_t*)d_ws;                            // 43*8*16*4*1024 = 22,544,384 B
    ushort_t* W2f = W1f + (size_t)J_TOT * D_DIM * D_DIM;        // 43*16KB        =    704,512 B
    float*    b2p = (float*)(W2f + (size_t)J_TOT * 16 * D_DIM); // 43*16*4        =      2,752 B

    pack_kernel<<<5504 + J_TOT, 256, 0, stream>>>(W1, W1f, W2a, b2a, W2b, b2b, W2f, b2p);
    MotionDecoder_36309653520632_kernel<<<NWG, 512, 0, stream>>>(
        x, b1, W1f, W2f, b2p, out);
}